// Round 1
// baseline (187.987 us; speedup 1.0000x reference)
//
#include <hip/hip_runtime.h>

// Problem constants (PARTViT pairwise head)
#define BB 64
#define NN 576
#define DD 768
#define KK 1024
#define ROWS (BB * NN)    // 36864 patch rows
#define PAIRS (BB * KK)   // 65536 pairs
// d_out layout: [PAIRS*2] f32 head output, then [PAIRS*2] f32 echoed indices
//
// R4: single fused kernel. Key insight: the projection table P is
// BATCH-LOCAL (pair (b,k) only gathers rows of batch b), and one batch's
// slice is 576*float4 = 9.2 KB -> fits LDS. One workgroup per batch:
//   phase 1: 16 waves compute P[0..575] of this batch into LDS
//            (wave-per-row, register-resident weights, butterfly reduce)
//   phase 2: __syncthreads(); 1024 threads each resolve one pair from LDS.
// Removes: second launch, K1->K2 grid-wide dependency, g_P device-global
// round-trip. The grid-wide barrier that sank R3 (cooperative launch under
// graph capture) was never needed - the dependency is block-local.
// Floor of our slice: z read 113 MB @ ~6.3 TB/s ~= 18 us + ~2 us pairs.

__global__ __launch_bounds__(1024) void partvit_fused(const float* __restrict__ z,
                                                      const int* __restrict__ idx,
                                                      const float* __restrict__ W,
                                                      const float* __restrict__ bh,
                                                      float* __restrict__ out) {
    __shared__ float4 P[NN];  // 9216 B: P[r] = {z_r.W[:768,0], z_r.W[:768,1],
                              //                 z_r.W[768:,0], z_r.W[768:,1]}
    const int b    = blockIdx.x;         // one workgroup per batch
    const int lane = threadIdx.x & 63;
    const int wave = threadIdx.x >> 6;   // 0..15

    // W is [1536,2] row-major: W[d,t] at 2*d+t -> float2 per d.
    // Lane l owns d = j*256 + 4l + c (j=0..2, c=0..3) of each half.
    const float2* __restrict__ W2 = (const float2*)W;
    float2 wa[3][4], wb[3][4];
#pragma unroll
    for (int j = 0; j < 3; ++j) {
#pragma unroll
        for (int c = 0; c < 4; ++c) {
            const int d = j * 256 + (lane << 2) + c;
            wa[j][c] = W2[d];        // first-half weights (patch-0 slot)
            wb[j][c] = W2[d + DD];   // second-half weights (patch-1 slot)
        }
    }

    // This batch's z slab: 576 rows * 192 float4, contiguous.
    const float4* __restrict__ z4 = (const float4*)z + (size_t)b * NN * 192;

    // Phase 1: wave w handles rows {w, w+16, w+32, ...}; 2-row unroll so 6
    // dwordx4 loads are in flight per wave before the FMA block (MLP for
    // the 64-CU-only grid: ~98 KB in flight/CU >> needed for 6.3 TB/s).
    for (int r = wave; r < NN; r += 32) {
        const int r2 = r + 16;
        float4 v0[3], v1[3];
#pragma unroll
        for (int j = 0; j < 3; ++j) v0[j] = z4[r  * 192 + j * 64 + lane];
#pragma unroll
        for (int j = 0; j < 3; ++j) v1[j] = z4[r2 * 192 + j * 64 + lane];

        float a00 = 0.f, a01 = 0.f, a10 = 0.f, a11 = 0.f;
        float c00 = 0.f, c01 = 0.f, c10 = 0.f, c11 = 0.f;
#pragma unroll
        for (int j = 0; j < 3; ++j) {
            a00 = fmaf(v0[j].x, wa[j][0].x, a00);
            a00 = fmaf(v0[j].y, wa[j][1].x, a00);
            a00 = fmaf(v0[j].z, wa[j][2].x, a00);
            a00 = fmaf(v0[j].w, wa[j][3].x, a00);
            a01 = fmaf(v0[j].x, wa[j][0].y, a01);
            a01 = fmaf(v0[j].y, wa[j][1].y, a01);
            a01 = fmaf(v0[j].z, wa[j][2].y, a01);
            a01 = fmaf(v0[j].w, wa[j][3].y, a01);
            a10 = fmaf(v0[j].x, wb[j][0].x, a10);
            a10 = fmaf(v0[j].y, wb[j][1].x, a10);
            a10 = fmaf(v0[j].z, wb[j][2].x, a10);
            a10 = fmaf(v0[j].w, wb[j][3].x, a10);
            a11 = fmaf(v0[j].x, wb[j][0].y, a11);
            a11 = fmaf(v0[j].y, wb[j][1].y, a11);
            a11 = fmaf(v0[j].z, wb[j][2].y, a11);
            a11 = fmaf(v0[j].w, wb[j][3].y, a11);

            c00 = fmaf(v1[j].x, wa[j][0].x, c00);
            c00 = fmaf(v1[j].y, wa[j][1].x, c00);
            c00 = fmaf(v1[j].z, wa[j][2].x, c00);
            c00 = fmaf(v1[j].w, wa[j][3].x, c00);
            c01 = fmaf(v1[j].x, wa[j][0].y, c01);
            c01 = fmaf(v1[j].y, wa[j][1].y, c01);
            c01 = fmaf(v1[j].z, wa[j][2].y, c01);
            c01 = fmaf(v1[j].w, wa[j][3].y, c01);
            c10 = fmaf(v1[j].x, wb[j][0].x, c10);
            c10 = fmaf(v1[j].y, wb[j][1].x, c10);
            c10 = fmaf(v1[j].z, wb[j][2].x, c10);
            c10 = fmaf(v1[j].w, wb[j][3].x, c10);
            c11 = fmaf(v1[j].x, wb[j][0].y, c11);
            c11 = fmaf(v1[j].y, wb[j][1].y, c11);
            c11 = fmaf(v1[j].z, wb[j][2].y, c11);
            c11 = fmaf(v1[j].w, wb[j][3].y, c11);
        }
#pragma unroll
        for (int off = 32; off > 0; off >>= 1) {
            a00 += __shfl_xor(a00, off, 64);
            a01 += __shfl_xor(a01, off, 64);
            a10 += __shfl_xor(a10, off, 64);
            a11 += __shfl_xor(a11, off, 64);
            c00 += __shfl_xor(c00, off, 64);
            c01 += __shfl_xor(c01, off, 64);
            c10 += __shfl_xor(c10, off, 64);
            c11 += __shfl_xor(c11, off, 64);
        }
        if (lane == 0) {
            P[r]  = make_float4(a00, a01, a10, a11);
            P[r2] = make_float4(c00, c01, c10, c11);
        }
    }

    __syncthreads();

    // Phase 2: one thread per pair of this batch. Indices clamped so a
    // dtype-contract surprise yields a clean absmax failure, not a fault.
    const int t = b * KK + (int)threadIdx.x;  // pair id = b*K + k
    const int2 id = ((const int2*)idx)[t];
    const int i0 = min(max(id.x, 0), NN - 1);
    const int i1 = min(max(id.y, 0), NN - 1);
    const float4 p0 = P[i0];
    const float4 p1 = P[i1];
    const float b0 = bh[0], b1 = bh[1];
    ((float2*)out)[t] = make_float2(p0.x + p1.z + b0, p0.y + p1.w + b1);
    ((float2*)out)[PAIRS + t] = make_float2((float)id.x, (float)id.y);
}

extern "C" void kernel_launch(void* const* d_in, const int* in_sizes, int n_in,
                              void* d_out, int out_size, void* d_ws, size_t ws_size,
                              hipStream_t stream) {
    const float* z   = (const float*)d_in[0];
    const int*   idx = (const int*)d_in[1];
    const float* W   = (const float*)d_in[2];
    const float* bh  = (const float*)d_in[3];
    float*       out = (float*)d_out;
    (void)d_ws; (void)ws_size; (void)in_sizes; (void)n_in; (void)out_size;

    // One workgroup per batch; 16 waves each (1024 threads).
    partvit_fused<<<BB, 1024, 0, stream>>>(z, idx, W, bh, out);
}